// Round 1
// baseline (557.820 us; speedup 1.0000x reference)
//
#include <hip/hip_runtime.h>
#include <cstdint>
#include <cstddef>

#define T_ 3
#define B_ 2
#define Y_ 192
#define X_ 192
#define YX_ 36864          // Y_*X_
#define N_ 221184          // T_*B_*Y_*X_
#define NS_ 73728          // B_*Y_*X_

typedef __attribute__((ext_vector_type(8))) short short8;
typedef __attribute__((ext_vector_type(4))) float f32x4;
typedef unsigned short u16;
typedef unsigned int u32;

__device__ __forceinline__ u16 f2bf(float f){
  u32 x = __builtin_bit_cast(u32, f);
  x += 0x7fffu + ((x >> 16) & 1u);          // RNE
  return (u16)(x >> 16);
}
__device__ __forceinline__ float bflo(u32 u){ return __builtin_bit_cast(float, u << 16); }
__device__ __forceinline__ float bfhi(u32 u){ return __builtin_bit_cast(float, u & 0xffff0000u); }
__device__ __forceinline__ int clampi(int v, int lo, int hi){ return v < lo ? lo : (v > hi ? hi : v); }

// ---------------- kernel 0: transpose weights to bf16, n-major ----------------
__global__ __launch_bounds__(256) void wt_kernel(
    const float* __restrict__ Wq, const float* __restrict__ Wk,
    const float* __restrict__ Wv, const float* __restrict__ Wo,
    u16* __restrict__ WT){
  int idx = blockIdx.x * 256 + threadIdx.x;     // 65536 total
  int g = idx >> 14;
  int r = (idx >> 7) & 127;                     // k
  int c = idx & 127;                            // n
  const float* W = (g == 0) ? Wq : (g == 1) ? Wk : (g == 2) ? Wv : Wo;
  WT[g * 16384 + c * 128 + r] = f2bf(W[r * 128 + c]);
}

// ---------------- kernel 1: fused QKV projection + embeddings ----------------
// grid (N_/128, 3); group 0=Q (temp+spatial emb), 1=K (temp emb), 2=V
__global__ __launch_bounds__(256) void qkv_kernel(
    const float* __restrict__ frames, const u16* __restrict__ WT,
    u16* __restrict__ Qb, u16* __restrict__ Kb, u16* __restrict__ Vb,
    const float* __restrict__ temp_emb, const float* __restrict__ spatial_emb){
  __shared__ float tile[128 * 128];
  const int tid = threadIdx.x;
  const int w = tid >> 6, l = tid & 63;
  const int l16 = l & 15, lg = l >> 4;
  const int g = blockIdx.y;
  const int m0 = blockIdx.x * 128;
  const u16* wt = WT + g * 16384;

  f32x4 acc[2][8];
  #pragma unroll
  for (int mr = 0; mr < 2; ++mr)
    #pragma unroll
    for (int nf = 0; nf < 8; ++nf)
      acc[mr][nf] = (f32x4){0.f, 0.f, 0.f, 0.f};

  #pragma unroll
  for (int ks = 0; ks < 4; ++ks){
    short8 af[2];
    #pragma unroll
    for (int mr = 0; mr < 2; ++mr){
      const float* ap = frames + (size_t)(m0 + w * 32 + mr * 16 + l16) * 128 + ks * 32 + lg * 8;
      const f32x4 a0 = *(const f32x4*)ap;
      const f32x4 a1 = *(const f32x4*)(ap + 4);
      short8 t;
      t[0] = (short)f2bf(a0[0]); t[1] = (short)f2bf(a0[1]);
      t[2] = (short)f2bf(a0[2]); t[3] = (short)f2bf(a0[3]);
      t[4] = (short)f2bf(a1[0]); t[5] = (short)f2bf(a1[1]);
      t[6] = (short)f2bf(a1[2]); t[7] = (short)f2bf(a1[3]);
      af[mr] = t;
    }
    #pragma unroll
    for (int nf = 0; nf < 8; ++nf){
      const short8 bf = *(const short8*)(wt + (nf * 16 + l16) * 128 + ks * 32 + lg * 8);
      acc[0][nf] = __builtin_amdgcn_mfma_f32_16x16x32_bf16(af[0], bf, acc[0][nf], 0, 0, 0);
      acc[1][nf] = __builtin_amdgcn_mfma_f32_16x16x32_bf16(af[1], bf, acc[1][nf], 0, 0, 0);
    }
  }

  // write acc -> LDS (row = pixel-in-tile, col = channel)
  #pragma unroll
  for (int mr = 0; mr < 2; ++mr)
    #pragma unroll
    for (int nf = 0; nf < 8; ++nf)
      #pragma unroll
      for (int i = 0; i < 4; ++i)
        tile[(w * 32 + mr * 16 + lg * 4 + i) * 128 + nf * 16 + l16] = acc[mr][nf][i];
  __syncthreads();

  u16* outp = (g == 0) ? Qb : (g == 1) ? Kb : Vb;
  #pragma unroll
  for (int it = 0; it < 16; ++it){
    const int idx = it * 256 + tid;
    const int r = idx >> 5;
    const int c4 = (idx & 31) * 4;
    f32x4 v = *(const f32x4*)&tile[r * 128 + c4];
    const int p = m0 + r;
    const int t = p / YX_ / B_;           // frame
    if (g <= 1){                          // temporal emb for Q and K
      const float* te = temp_emb + t * 128 + c4;
      v[0] += te[0]; v[1] += te[1]; v[2] += te[2]; v[3] += te[3];
    }
    if (g == 0){                          // query spatial emb
      const int yx = p % YX_;
      const int y = yx / X_, x = yx % X_;
      const int yrel = y - clampi(y, 2, Y_ - 3) + 2;
      const int xrel = x - clampi(x, 2, X_ - 3) + 2;
      const float* se = spatial_emb + (yrel * 5 + xrel) * 128 + c4;
      v[0] += se[0]; v[1] += se[1]; v[2] += se[2]; v[3] += se[3];
    }
    uint2 pk;
    pk.x = (u32)f2bf(v[0]) | ((u32)f2bf(v[1]) << 16);
    pk.y = (u32)f2bf(v[2]) | ((u32)f2bf(v[3]) << 16);
    *(uint2*)(outp + (size_t)p * 128 + c4) = pk;
  }
}

// ---------------- kernel 2: local spatio-temporal attention ----------------
// 1 wave per site (b,y,x); 4 sites per block. Writes attn output over Qb.
__global__ __launch_bounds__(256) void attn_kernel(
    const u16* __restrict__ Kb, const u16* __restrict__ Vb,
    u16* __restrict__ Qb, const float* __restrict__ spatial_emb){
  __shared__ float qse[4][3][25][8];
  const int tid = threadIdx.x;
  const int w = tid >> 6, l = tid & 63;
  const int g = l >> 4, c16 = l & 15, h = c16 >> 1;
  const int site = blockIdx.x * 4 + w;
  const int b = site / YX_;
  const int yx = site % YX_;
  const int y = yx / X_, x = yx % X_;
  const int yc = clampi(y, 2, Y_ - 3), xc = clampi(x, 2, X_ - 3);

  // load Q (3 query frames), pre-scaled by 1/sqrt(F) = 0.25
  float q[3][8];
  #pragma unroll
  for (int qq = 0; qq < 3; ++qq){
    const size_t nq = (size_t)(((qq * B_ + b) * Y_ + y) * X_ + x) * 128 + c16 * 8;
    const uint4 u = *(const uint4*)(Qb + nq);
    q[qq][0] = bflo(u.x) * 0.25f; q[qq][1] = bfhi(u.x) * 0.25f;
    q[qq][2] = bflo(u.y) * 0.25f; q[qq][3] = bfhi(u.y) * 0.25f;
    q[qq][4] = bflo(u.z) * 0.25f; q[qq][5] = bfhi(u.z) * 0.25f;
    q[qq][6] = bflo(u.w) * 0.25f; q[qq][7] = bfhi(u.w) * 0.25f;
  }

  // qse[q][s][h] = (scaled Q) . spatial_emb[s]  (per head)
  #pragma unroll
  for (int j = 0; j < 7; ++j){
    const int s = g + 4 * j;
    if (s < 25){
      const float* se = spatial_emb + s * 128 + c16 * 8;
      #pragma unroll
      for (int qq = 0; qq < 3; ++qq){
        float d = q[qq][0]*se[0] + q[qq][1]*se[1] + q[qq][2]*se[2] + q[qq][3]*se[3]
                + q[qq][4]*se[4] + q[qq][5]*se[5] + q[qq][6]*se[6] + q[qq][7]*se[7];
        d += __shfl_xor(d, 1);
        if (!(l & 1)) qse[w][qq][s][h] = d;
      }
    }
  }
  __syncthreads();

  float m[3]  = {-__builtin_inff(), -__builtin_inff(), -__builtin_inff()};
  float ll[3] = {0.f, 0.f, 0.f};
  float acc[3][8];
  #pragma unroll
  for (int qq = 0; qq < 3; ++qq)
    #pragma unroll
    for (int c = 0; c < 8; ++c) acc[qq][c] = 0.f;

  // 75 keys strided across 4 lane-groups: group g handles keys g, g+4, ...
  for (int j = 0; j < 19; ++j){
    const int kk = g + 4 * j;
    const bool valid = (kk < 75);
    const int kk2 = valid ? kk : 0;
    const int t = kk2 / 25, s = kk2 % 25;
    const int ky = yc + s / 5 - 2, kx = xc + s % 5 - 2;
    const size_t nk = (size_t)(((t * B_ + b) * Y_ + ky) * X_ + kx) * 128 + c16 * 8;
    const uint4 uk = *(const uint4*)(Kb + nk);
    const uint4 uv = *(const uint4*)(Vb + nk);
    float kf[8], vf[8];
    kf[0] = bflo(uk.x); kf[1] = bfhi(uk.x); kf[2] = bflo(uk.y); kf[3] = bfhi(uk.y);
    kf[4] = bflo(uk.z); kf[5] = bfhi(uk.z); kf[6] = bflo(uk.w); kf[7] = bfhi(uk.w);
    vf[0] = bflo(uv.x); vf[1] = bfhi(uv.x); vf[2] = bflo(uv.y); vf[3] = bfhi(uv.y);
    vf[4] = bflo(uv.z); vf[5] = bfhi(uv.z); vf[6] = bflo(uv.w); vf[7] = bfhi(uv.w);

    #pragma unroll
    for (int qq = 0; qq < 3; ++qq){
      float d = q[qq][0]*kf[0] + q[qq][1]*kf[1] + q[qq][2]*kf[2] + q[qq][3]*kf[3]
              + q[qq][4]*kf[4] + q[qq][5]*kf[5] + q[qq][6]*kf[6] + q[qq][7]*kf[7];
      d += __shfl_xor(d, 1);
      d += qse[w][qq][s][h];
      if (!valid) d = -__builtin_inff();
      if (d <= m[qq]){                       // common path: max unchanged
        const float p = __expf(d - m[qq]);
        ll[qq] += p;
        #pragma unroll
        for (int c = 0; c < 8; ++c) acc[qq][c] += p * vf[c];
      } else {                               // new max: p == 1 exactly
        const float al = __expf(m[qq] - d);
        m[qq] = d;
        ll[qq] = ll[qq] * al + 1.f;
        #pragma unroll
        for (int c = 0; c < 8; ++c) acc[qq][c] = acc[qq][c] * al + vf[c];
      }
    }
  }

  // merge the 4 per-group partial softmax states (lanes l, l^16, l^32, l^48)
  #pragma unroll
  for (int qq = 0; qq < 3; ++qq){
    float M = m[qq];
    M = fmaxf(M, __shfl_xor(M, 16));
    M = fmaxf(M, __shfl_xor(M, 32));
    const float sg = __expf(m[qq] - M);
    float lt = ll[qq] * sg;
    lt += __shfl_xor(lt, 16);
    lt += __shfl_xor(lt, 32);
    const float inv = 1.0f / lt;
    #pragma unroll
    for (int c = 0; c < 8; ++c){
      float a = acc[qq][c] * sg;
      a += __shfl_xor(a, 16);
      a += __shfl_xor(a, 32);
      acc[qq][c] = a * inv;
    }
  }

  // group qq (<3) stores query frame qq's output over its Q row
  #pragma unroll
  for (int qq = 0; qq < 3; ++qq){
    if (g == qq){
      uint4 pk;
      pk.x = (u32)f2bf(acc[qq][0]) | ((u32)f2bf(acc[qq][1]) << 16);
      pk.y = (u32)f2bf(acc[qq][2]) | ((u32)f2bf(acc[qq][3]) << 16);
      pk.z = (u32)f2bf(acc[qq][4]) | ((u32)f2bf(acc[qq][5]) << 16);
      pk.w = (u32)f2bf(acc[qq][6]) | ((u32)f2bf(acc[qq][7]) << 16);
      const size_t nq = (size_t)(((qq * B_ + b) * Y_ + y) * X_ + x) * 128 + c16 * 8;
      *(uint4*)(Qb + nq) = pk;
    }
  }
}

// ---------------- kernel 3: output projection (attnout x Wout) ----------------
__global__ __launch_bounds__(256) void out_kernel(
    const u16* __restrict__ Ab, const u16* __restrict__ WT3, float* __restrict__ out){
  const int tid = threadIdx.x;
  const int w = tid >> 6, l = tid & 63;
  const int l16 = l & 15, lg = l >> 4;
  const int m0 = blockIdx.x * 128;

  f32x4 acc[2][8];
  #pragma unroll
  for (int mr = 0; mr < 2; ++mr)
    #pragma unroll
    for (int nf = 0; nf < 8; ++nf)
      acc[mr][nf] = (f32x4){0.f, 0.f, 0.f, 0.f};

  #pragma unroll
  for (int ks = 0; ks < 4; ++ks){
    short8 af[2];
    #pragma unroll
    for (int mr = 0; mr < 2; ++mr)
      af[mr] = *(const short8*)(Ab + (size_t)(m0 + w * 32 + mr * 16 + l16) * 128 + ks * 32 + lg * 8);
    #pragma unroll
    for (int nf = 0; nf < 8; ++nf){
      const short8 bf = *(const short8*)(WT3 + (nf * 16 + l16) * 128 + ks * 32 + lg * 8);
      acc[0][nf] = __builtin_amdgcn_mfma_f32_16x16x32_bf16(af[0], bf, acc[0][nf], 0, 0, 0);
      acc[1][nf] = __builtin_amdgcn_mfma_f32_16x16x32_bf16(af[1], bf, acc[1][nf], 0, 0, 0);
    }
  }

  #pragma unroll
  for (int mr = 0; mr < 2; ++mr)
    #pragma unroll
    for (int nf = 0; nf < 8; ++nf)
      #pragma unroll
      for (int i = 0; i < 4; ++i)
        out[(size_t)(m0 + w * 32 + mr * 16 + lg * 4 + i) * 128 + nf * 16 + l16] = acc[mr][nf][i];
}

extern "C" void kernel_launch(void* const* d_in, const int* in_sizes, int n_in,
                              void* d_out, int out_size, void* d_ws, size_t ws_size,
                              hipStream_t stream){
  const float* frames      = (const float*)d_in[0];
  const float* Wq          = (const float*)d_in[1];
  const float* Wk          = (const float*)d_in[2];
  const float* Wv          = (const float*)d_in[3];
  const float* Wo          = (const float*)d_in[4];
  const float* temp_emb    = (const float*)d_in[5];
  const float* spatial_emb = (const float*)d_in[6];

  u16* WT = (u16*)d_ws;                        // [4][128][128] bf16 (n-major)
  u16* Qb = WT + 4 * 16384;                    // [N_][128] bf16 (Q, then attnout)
  u16* Kb = (u16*)d_out;                       // [N_][128] bf16 — reuse output buffer
  u16* Vb = Kb + (size_t)N_ * 128;             // [N_][128] bf16 — exactly fills d_out
  float* out = (float*)d_out;

  wt_kernel<<<256, 256, 0, stream>>>(Wq, Wk, Wv, Wo, WT);
  qkv_kernel<<<dim3(N_ / 128, 3), 256, 0, stream>>>(frames, WT, Qb, Kb, Vb, temp_emb, spatial_emb);
  attn_kernel<<<NS_ / 4, 256, 0, stream>>>(Kb, Vb, Qb, spatial_emb);
  out_kernel<<<N_ / 128, 256, 0, stream>>>(Qb, WT + 3 * 16384, out);
}